// Round 1
// baseline (1740.904 us; speedup 1.0000x reference)
//
#include <hip/hip_runtime.h>
#include <cstdint>
#include <cstddef>

#define K_DIM 4096
#define TILE  128
#define BK    32

typedef __bf16 bf16x8 __attribute__((ext_vector_type(8)));
typedef float  f32x4  __attribute__((ext_vector_type(4)));

__device__ __forceinline__ unsigned int pack2_bf16_rne(float lo, float hi) {
    unsigned int ulo = __float_as_uint(lo);
    unsigned int uhi = __float_as_uint(hi);
    ulo += 0x7fffu + ((ulo >> 16) & 1u);
    uhi += 0x7fffu + ((uhi >> 16) & 1u);
    return (ulo >> 16) | (uhi & 0xffff0000u);
}

// x: fp32 -> bf16, 8 elems/thread
__global__ void cvt_x_kernel(const float* __restrict__ in,
                             unsigned short* __restrict__ out, size_t n8) {
    size_t i = (size_t)blockIdx.x * blockDim.x + threadIdx.x;
    if (i >= n8) return;
    const float4* p = (const float4*)in + i * 2;
    float4 a = p[0], b = p[1];
    uint4 r;
    r.x = pack2_bf16_rne(a.x, a.y);
    r.y = pack2_bf16_rne(a.z, a.w);
    r.z = pack2_bf16_rne(b.x, b.y);
    r.w = pack2_bf16_rne(b.z, b.w);
    ((uint4*)out)[i] = r;
}

// weight * wscales[row] : fp32 -> bf16, 8 elems/thread (K=4096 divisible by 8,
// so all 8 elems share a row)
__global__ void cvt_w_kernel(const float* __restrict__ w,
                             const float* __restrict__ s,
                             unsigned short* __restrict__ out, size_t n8) {
    size_t i = (size_t)blockIdx.x * blockDim.x + threadIdx.x;
    if (i >= n8) return;
    int row = (int)((i * 8) >> 12);  // / K_DIM
    float sc = s[row];
    const float4* p = (const float4*)w + i * 2;
    float4 a = p[0], b = p[1];
    uint4 r;
    r.x = pack2_bf16_rne(a.x * sc, a.y * sc);
    r.y = pack2_bf16_rne(a.z * sc, a.w * sc);
    r.z = pack2_bf16_rne(b.x * sc, b.y * sc);
    r.w = pack2_bf16_rne(b.z * sc, b.w * sc);
    ((uint4*)out)[i] = r;
}

// C[m,n] = sum_k A[m,k] * B[n,k] + bias[n]
// A: [M,K] bf16 row-major; B: [N,K] bf16 row-major (B^T GEMM); C: [M,N] fp32.
// 128x128 tile per 256-thread block (4 waves in 2x2, 64x64 each as 4x4 MFMA
// tiles of 16x16x32). global_load_lds width=16 staging, BK=32.
__global__ void gemm_bf16_bt(const unsigned short* __restrict__ A,
                             const unsigned short* __restrict__ B,
                             const float* __restrict__ bias,
                             float* __restrict__ C, int M, int N) {
    __shared__ unsigned short lsA[TILE * BK];  // 8 KB
    __shared__ unsigned short lsB[TILE * BK];  // 8 KB

    const int t = threadIdx.x;
    const int l = t & 63;
    const int w = t >> 6;
    const int wm = w >> 1, wn = w & 1;

    const int rowBase = blockIdx.y * TILE;
    const int colBase = blockIdx.x * TILE;

    f32x4 acc[4][4];
#pragma unroll
    for (int i = 0; i < 4; i++)
#pragma unroll
        for (int j = 0; j < 4; j++) acc[i][j] = (f32x4){0.f, 0.f, 0.f, 0.f};

    // staging: thread t loads 16B at (row = t>>2 [+64 per issue], col = (t&3)*8)
    // LDS offset = issue*2048 + t*8 ushorts -> wave-uniform base + lane*16B
    const int arow = t >> 2;
    const int acol = (t & 3) * 8;
    const unsigned short* gA = A + (size_t)(rowBase + arow) * K_DIM + acol;
    const unsigned short* gB = B + (size_t)(colBase + arow) * K_DIM + acol;

    // fragment offsets: A frag lane l holds A[m=l&15][k=(l>>4)*8+j]
    const int q = l >> 4;
    const int mn = l & 15;
    const int aoff0 = (wm * 64 + mn) * BK + q * 8;
    const int boff0 = (wn * 64 + mn) * BK + q * 8;

    for (int k0 = 0; k0 < K_DIM; k0 += BK) {
#pragma unroll
        for (int i = 0; i < 2; i++) {
            __builtin_amdgcn_global_load_lds(
                (const __attribute__((address_space(1))) unsigned int*)(gA + (size_t)i * 64 * K_DIM + k0),
                (__attribute__((address_space(3))) unsigned int*)(&lsA[i * 2048 + t * 8]),
                16, 0, 0);
            __builtin_amdgcn_global_load_lds(
                (const __attribute__((address_space(1))) unsigned int*)(gB + (size_t)i * 64 * K_DIM + k0),
                (__attribute__((address_space(3))) unsigned int*)(&lsB[i * 2048 + t * 8]),
                16, 0, 0);
        }
        __syncthreads();

        bf16x8 aF[4], bF[4];
#pragma unroll
        for (int i = 0; i < 4; i++) {
            aF[i] = *(const bf16x8*)&lsA[aoff0 + i * 16 * BK];
            bF[i] = *(const bf16x8*)&lsB[boff0 + i * 16 * BK];
        }
#pragma unroll
        for (int i = 0; i < 4; i++)
#pragma unroll
            for (int j = 0; j < 4; j++)
                acc[i][j] = __builtin_amdgcn_mfma_f32_16x16x32_bf16(aF[i], bF[j], acc[i][j], 0, 0, 0);
        __syncthreads();
    }

    // C/D layout (m89-verified): col = lane&15, row = (lane>>4)*4 + reg
#pragma unroll
    for (int j = 0; j < 4; j++) {
        const int col = colBase + wn * 64 + j * 16 + mn;
        const float bv = bias[col];
#pragma unroll
        for (int i = 0; i < 4; i++) {
            const int row0 = rowBase + wm * 64 + i * 16 + q * 4;
#pragma unroll
            for (int r = 0; r < 4; r++) {
                C[(size_t)(row0 + r) * N + col] = acc[i][j][r] + bv;
            }
        }
    }
}

// Emergency fallback if ws_size can't hold the bf16 copies (slow but correct).
__global__ void gemm_f32_fallback(const float* __restrict__ X,
                                  const float* __restrict__ W,
                                  const float* __restrict__ S,
                                  const float* __restrict__ bias,
                                  float* __restrict__ C, int M, int N) {
    __shared__ float sx[16][17];
    __shared__ float sw[16][17];
    int tx = threadIdx.x, ty = threadIdx.y;
    int row = blockIdx.y * 16 + ty;
    int col = blockIdx.x * 16 + tx;
    float acc = 0.f;
    for (int k0 = 0; k0 < K_DIM; k0 += 16) {
        sx[ty][tx] = X[(size_t)row * K_DIM + k0 + tx];
        sw[ty][tx] = W[(size_t)(blockIdx.x * 16 + ty) * K_DIM + k0 + tx];
        __syncthreads();
#pragma unroll
        for (int kk = 0; kk < 16; kk++) acc += sx[ty][kk] * sw[tx][kk];
        __syncthreads();
    }
    C[(size_t)row * N + col] = acc * S[col] + bias[col];
}

extern "C" void kernel_launch(void* const* d_in, const int* in_sizes, int n_in,
                              void* d_out, int out_size, void* d_ws, size_t ws_size,
                              hipStream_t stream) {
    const float* x    = (const float*)d_in[0];  // [B,S,K]
    const float* wgt  = (const float*)d_in[1];  // [N,K]
    const float* wsc  = (const float*)d_in[2];  // [N,1]
    const float* bias = (const float*)d_in[3];  // [1,N]
    float* out = (float*)d_out;                 // [B,S,N] = [M,N]

    const size_t M = (size_t)in_sizes[0] / K_DIM;  // 8192
    const size_t N = (size_t)in_sizes[2];          // 11008

    const size_t xb_elems = M * K_DIM;
    const size_t wb_elems = N * K_DIM;
    const size_t need = (xb_elems + wb_elems) * sizeof(unsigned short);

    if (ws_size >= need) {
        unsigned short* xb = (unsigned short*)d_ws;
        unsigned short* wb = xb + xb_elems;
        cvt_x_kernel<<<dim3((unsigned)(xb_elems / 8 / 256)), 256, 0, stream>>>(x, xb, xb_elems / 8);
        cvt_w_kernel<<<dim3((unsigned)(wb_elems / 8 / 256)), 256, 0, stream>>>(wgt, wsc, wb, wb_elems / 8);
        gemm_bf16_bt<<<dim3((unsigned)(N / TILE), (unsigned)(M / TILE)), 256, 0, stream>>>(
            xb, wb, bias, out, (int)M, (int)N);
    } else {
        gemm_f32_fallback<<<dim3((unsigned)(N / 16), (unsigned)(M / 16)), dim3(16, 16), 0, stream>>>(
            x, wgt, wsc, bias, out, (int)M, (int)N);
    }
}

// Round 3
// 1490.430 us; speedup vs baseline: 1.1681x; 1.1681x over previous
//
#include <hip/hip_runtime.h>
#include <cstdint>
#include <cstddef>

#define K_DIM 4096
#define TILE  128
#define BK    32
#define GROUP_M 8

typedef __bf16 bf16x8 __attribute__((ext_vector_type(8)));
typedef float  f32x4  __attribute__((ext_vector_type(4)));
typedef unsigned int u32x4 __attribute__((ext_vector_type(4)));

__device__ __forceinline__ unsigned int pack2_bf16_rne(float lo, float hi) {
    unsigned int ulo = __float_as_uint(lo);
    unsigned int uhi = __float_as_uint(hi);
    ulo += 0x7fffu + ((ulo >> 16) & 1u);
    uhi += 0x7fffu + ((uhi >> 16) & 1u);
    return (ulo >> 16) | (uhi & 0xffff0000u);
}

// x: fp32 -> bf16, 8 elems/thread. NT loads: x is read exactly once.
__global__ void cvt_x_kernel(const float* __restrict__ in,
                             unsigned short* __restrict__ out, size_t n8) {
    size_t i = (size_t)blockIdx.x * blockDim.x + threadIdx.x;
    if (i >= n8) return;
    const f32x4* p = (const f32x4*)in + i * 2;
    f32x4 a = __builtin_nontemporal_load(p);
    f32x4 b = __builtin_nontemporal_load(p + 1);
    u32x4 r;
    r.x = pack2_bf16_rne(a.x, a.y);
    r.y = pack2_bf16_rne(a.z, a.w);
    r.z = pack2_bf16_rne(b.x, b.y);
    r.w = pack2_bf16_rne(b.z, b.w);
    *((u32x4*)out + i) = r;
}

// weight * wscales[row] : fp32 -> bf16, 8 elems/thread (row-uniform per thread)
__global__ void cvt_w_kernel(const float* __restrict__ w,
                             const float* __restrict__ s,
                             unsigned short* __restrict__ out, size_t n8) {
    size_t i = (size_t)blockIdx.x * blockDim.x + threadIdx.x;
    if (i >= n8) return;
    int row = (int)((i * 8) >> 12);  // / K_DIM
    float sc = s[row];
    const f32x4* p = (const f32x4*)w + i * 2;
    f32x4 a = __builtin_nontemporal_load(p);
    f32x4 b = __builtin_nontemporal_load(p + 1);
    u32x4 r;
    r.x = pack2_bf16_rne(a.x * sc, a.y * sc);
    r.y = pack2_bf16_rne(a.z * sc, a.w * sc);
    r.z = pack2_bf16_rne(b.x * sc, b.y * sc);
    r.w = pack2_bf16_rne(b.z * sc, b.w * sc);
    *((u32x4*)out + i) = r;
}

// C[m,n] = sum_k A[m,k]*B[n,k] + bias[n]; A [M,K], B [N,K] bf16; C [M,N] fp32.
// 128x128/block, 4 waves 2x2. Grouped swizzle for L2 locality, XOR-swizzled
// LDS layout for conflict-free ds_read_b128, NT epilogue stores.
__global__ void gemm_bf16_bt(const unsigned short* __restrict__ A,
                             const unsigned short* __restrict__ B,
                             const float* __restrict__ bias,
                             float* __restrict__ C, int M, int N) {
    __shared__ unsigned short lsA[TILE * BK];  // 8 KB
    __shared__ unsigned short lsB[TILE * BK];  // 8 KB

    const int t = threadIdx.x;
    const int l = t & 63;
    const int w = t >> 6;
    const int wm = w >> 1, wn = w & 1;

    // ---- grouped block swizzle (band of GROUP_M block-rows, sweep N) ----
    const int num_m = M / TILE;                 // 64
    const int num_n = N / TILE;                 // 86
    int pid = blockIdx.x;
    int wide = GROUP_M * num_n;
    int gid = pid / wide;
    int first_m = gid * GROUP_M;
    int gsz = min(GROUP_M, num_m - first_m);
    int pm = first_m + (pid % gsz);
    int pn = (pid % wide) / gsz;
    const int rowBase = pm * TILE;
    const int colBase = pn * TILE;

    f32x4 acc[4][4];
#pragma unroll
    for (int i = 0; i < 4; i++)
#pragma unroll
        for (int j = 0; j < 4; j++) acc[i][j] = (f32x4){0.f, 0.f, 0.f, 0.f};

    // ---- staging with XOR swizzle ----
    // LDS row R (tile-local), chunk-position p holds global 16B chunk p ^ s(R),
    // s(R) = (R&3) ^ ((R>>2)&3). Write addr stays t*8 (wave-uniform + lane*16B).
    const int r_loc = t >> 2;                        // 0..63 per issue
    const int sw_st = (r_loc & 3) ^ ((r_loc >> 2) & 3);
    const int ck    = (t & 3) ^ sw_st;               // swizzled global chunk
    const int acol  = ck * 8;
    const unsigned short* gA = A + (size_t)(rowBase + r_loc) * K_DIM + acol;
    const unsigned short* gB = B + (size_t)(colBase + r_loc) * K_DIM + acol;

    // ---- fragment read offsets (apply same XOR) ----
    const int q = l >> 4;                            // chunk 0..3 (k-slice)
    const int mn = l & 15;                           // row within 16
    const int sw_rd = (mn & 3) ^ ((mn >> 2) & 3);
    const int qp = q ^ sw_rd;                        // swizzled chunk position
    const int aoff0 = (wm * 64 + mn) * BK + qp * 8;
    const int boff0 = (wn * 64 + mn) * BK + qp * 8;

    for (int k0 = 0; k0 < K_DIM; k0 += BK) {
#pragma unroll
        for (int i = 0; i < 2; i++) {
            __builtin_amdgcn_global_load_lds(
                (const __attribute__((address_space(1))) unsigned int*)(gA + (size_t)i * 64 * K_DIM + k0),
                (__attribute__((address_space(3))) unsigned int*)(&lsA[i * 2048 + t * 8]),
                16, 0, 0);
            __builtin_amdgcn_global_load_lds(
                (const __attribute__((address_space(1))) unsigned int*)(gB + (size_t)i * 64 * K_DIM + k0),
                (__attribute__((address_space(3))) unsigned int*)(&lsB[i * 2048 + t * 8]),
                16, 0, 0);
        }
        __syncthreads();

        bf16x8 aF[4], bF[4];
#pragma unroll
        for (int i = 0; i < 4; i++) {
            aF[i] = *(const bf16x8*)&lsA[aoff0 + i * 16 * BK];
            bF[i] = *(const bf16x8*)&lsB[boff0 + i * 16 * BK];
        }
#pragma unroll
        for (int i = 0; i < 4; i++)
#pragma unroll
            for (int j = 0; j < 4; j++)
                acc[i][j] = __builtin_amdgcn_mfma_f32_16x16x32_bf16(aF[i], bF[j], acc[i][j], 0, 0, 0);
        __syncthreads();
    }

    // C/D layout (m89): col = lane&15, row = (lane>>4)*4 + reg.
    // NT stores: C is write-once, keep it out of L2 so A/B panels stay hot.
#pragma unroll
    for (int j = 0; j < 4; j++) {
        const int col = colBase + wn * 64 + j * 16 + mn;
        const float bv = bias[col];
#pragma unroll
        for (int i = 0; i < 4; i++) {
            const int row0 = rowBase + wm * 64 + i * 16 + q * 4;
#pragma unroll
            for (int r = 0; r < 4; r++) {
                __builtin_nontemporal_store(acc[i][j][r] + bv,
                                            &C[(size_t)(row0 + r) * N + col]);
            }
        }
    }
}

// Emergency fallback if ws_size can't hold the bf16 copies (slow but correct).
__global__ void gemm_f32_fallback(const float* __restrict__ X,
                                  const float* __restrict__ W,
                                  const float* __restrict__ S,
                                  const float* __restrict__ bias,
                                  float* __restrict__ C, int M, int N) {
    __shared__ float sx[16][17];
    __shared__ float sw[16][17];
    int tx = threadIdx.x, ty = threadIdx.y;
    int row = blockIdx.y * 16 + ty;
    int col = blockIdx.x * 16 + tx;
    float acc = 0.f;
    for (int k0 = 0; k0 < K_DIM; k0 += 16) {
        sx[ty][tx] = X[(size_t)row * K_DIM + k0 + tx];
        sw[ty][tx] = W[(size_t)(blockIdx.x * 16 + ty) * K_DIM + k0 + tx];
        __syncthreads();
#pragma unroll
        for (int kk = 0; kk < 16; kk++) acc += sx[ty][kk] * sw[tx][kk];
        __syncthreads();
    }
    C[(size_t)row * N + col] = acc * S[col] + bias[col];
}

extern "C" void kernel_launch(void* const* d_in, const int* in_sizes, int n_in,
                              void* d_out, int out_size, void* d_ws, size_t ws_size,
                              hipStream_t stream) {
    const float* x    = (const float*)d_in[0];  // [B,S,K]
    const float* wgt  = (const float*)d_in[1];  // [N,K]
    const float* wsc  = (const float*)d_in[2];  // [N,1]
    const float* bias = (const float*)d_in[3];  // [1,N]
    float* out = (float*)d_out;                 // [M,N]

    const size_t M = (size_t)in_sizes[0] / K_DIM;  // 8192
    const size_t N = (size_t)in_sizes[2];          // 11008

    const size_t xb_elems = M * K_DIM;
    const size_t wb_elems = N * K_DIM;
    const size_t need = (xb_elems + wb_elems) * sizeof(unsigned short);

    if (ws_size >= need) {
        unsigned short* xb = (unsigned short*)d_ws;
        unsigned short* wb = xb + xb_elems;
        cvt_x_kernel<<<dim3((unsigned)(xb_elems / 8 / 256)), 256, 0, stream>>>(x, xb, xb_elems / 8);
        cvt_w_kernel<<<dim3((unsigned)(wb_elems / 8 / 256)), 256, 0, stream>>>(wgt, wsc, wb, wb_elems / 8);
        const unsigned nblk = (unsigned)((M / TILE) * (N / TILE));
        gemm_bf16_bt<<<dim3(nblk), 256, 0, stream>>>(xb, wb, bias, out, (int)M, (int)N);
    } else {
        gemm_f32_fallback<<<dim3((unsigned)(N / 16), (unsigned)(M / 16)), dim3(16, 16), 0, stream>>>(
            x, wgt, wsc, bias, out, (int)M, (int)N);
    }
}